// Round 6
// baseline (1548.400 us; speedup 1.0000x reference)
//
#include <hip/hip_runtime.h>

#define NF0 300
#define F1 128
#define F2 64

// ---------------- CSR build: node hist -> bucket scan -> bucketed scatter -> local fill ----

__global__ void hist_k(const int* __restrict__ dst, int* __restrict__ cnt, int E) {
    int i = blockIdx.x * blockDim.x + threadIdx.x;
    int stride = gridDim.x * blockDim.x;
    for (; i < E; i += stride) atomicAdd(&cnt[dst[i]], 1);
}

// bucket = 128 consecutive nodes; bucket_cnt[b] = sum of node counts
__global__ __launch_bounds__(128) void bucket_sum_k(const int* __restrict__ cnt, int* __restrict__ bcnt, int n) {
    __shared__ int s[128];
    int i = (blockIdx.x << 7) + threadIdx.x;
    s[threadIdx.x] = (i < n) ? cnt[i] : 0;
    __syncthreads();
    for (int d = 64; d > 0; d >>= 1) {
        if (threadIdx.x < d) s[threadIdx.x] += s[threadIdx.x + d];
        __syncthreads();
    }
    if (threadIdx.x == 0) bcnt[blockIdx.x] = s[0];
}

// single-block exclusive scan over nb (<=1024) buckets; also seeds cursors and offs[n]
__global__ __launch_bounds__(1024) void bucket_scan_k(const int* __restrict__ bcnt, int* __restrict__ boffs,
                                                      int* __restrict__ bcur, int nb, int E,
                                                      int* __restrict__ offs, int n) {
    __shared__ int s[1024];
    int v = (threadIdx.x < nb) ? bcnt[threadIdx.x] : 0;
    s[threadIdx.x] = v;
    __syncthreads();
    for (int d = 1; d < 1024; d <<= 1) {
        int t = (threadIdx.x >= (unsigned)d) ? s[threadIdx.x - d] : 0;
        __syncthreads();
        s[threadIdx.x] += t;
        __syncthreads();
    }
    if (threadIdx.x < nb) {
        int e = s[threadIdx.x] - v;
        boffs[threadIdx.x] = e;
        bcur[threadIdx.x] = e;
    }
    if (threadIdx.x == 0) { boffs[nb] = E; offs[n] = E; }
}

// scatter edges into bucket-sorted ebuf; packed (src<<7)|(dst&127) (src < 2^17, bucket=128 nodes)
__global__ void bscatter_k(const int* __restrict__ src, const int* __restrict__ dst,
                           int* __restrict__ bcur, int* __restrict__ ebuf, int E) {
    int i = blockIdx.x * blockDim.x + threadIdx.x;
    int stride = gridDim.x * blockDim.x;
    for (; i < E; i += stride) {
        int d = dst[i];
        int p = atomicAdd(&bcur[d >> 7], 1);
        ebuf[p] = (src[i] << 7) | (d & 127);
    }
}

// per bucket: exact node offs + dinv via LDS scan of 128 counts, then LDS-cursor scatter of
// the bucket's edges into its contiguous slots window (L2-resident -> ~1x writeback)
__global__ __launch_bounds__(256) void local_fill_k(const int* __restrict__ cnt, const int* __restrict__ boffs,
                                                    const int* __restrict__ ebuf, int* __restrict__ offs,
                                                    float* __restrict__ dinv, int* __restrict__ slots, int n) {
    __shared__ int lval[128];
    __shared__ int lcur[128];
    int tid = threadIdx.x;
    int node0 = blockIdx.x << 7;
    int nn = min(128, n - node0);
    int c = 0;
    if (tid < 128) {
        c = (tid < nn) ? cnt[node0 + tid] : 0;
        lval[tid] = c;
    }
    __syncthreads();
    for (int d = 1; d < 128; d <<= 1) {
        int t = 0;
        if (tid < 128 && tid >= d) t = lval[tid - d];
        __syncthreads();
        if (tid < 128) lval[tid] += t;
        __syncthreads();
    }
    int boff = boffs[blockIdx.x];
    if (tid < 128) {
        int excl = lval[tid] - c;  // exclusive prefix within bucket
        if (tid < nn) {
            offs[node0 + tid] = boff + excl;
            dinv[node0 + tid] = rsqrtf((float)c + 1.0f);  // +1 self-loop
        }
        lcur[tid] = boff + excl;
    }
    __syncthreads();
    int end = boffs[blockIdx.x + 1];
    for (int j = boff + tid; j < end; j += 256) {
        int e = ebuf[j];
        int p = atomicAdd(&lcur[e & 127], 1);
        slots[p] = e >> 7;
    }
}

// ---------------- GEMM1: canonical LDS-tiled, 128x128 tile, 8x8 micro-tile ----------------
__global__ __launch_bounds__(256) void gemm1_k(const float* __restrict__ x, const float* __restrict__ W1,
                                               const float* __restrict__ dinv, float* __restrict__ y1, int n) {
    __shared__ float As[20][132];
    __shared__ float Bs[20][128];
    int tid = threadIdx.x;
    int cx = tid & 15;
    int ry = tid >> 4;
    int rowbase = blockIdx.x * 128;
    float acc[8][8];
#pragma unroll
    for (int i = 0; i < 8; ++i)
#pragma unroll
        for (int j = 0; j < 8; ++j) acc[i][j] = 0.f;

    int srow = tid >> 1;
    int shalf = tid & 1;
    int grow = min(rowbase + srow, n - 1);
    const float* xrow = x + (size_t)grow * NF0 + shalf * 10;

    for (int kt = 0; kt < NF0; kt += 20) {
        __syncthreads();
#pragma unroll
        for (int j = 0; j < 10; ++j) As[shalf * 10 + j][srow] = xrow[kt + j];
#pragma unroll
        for (int v = 0; v < 10; ++v) {
            int i = tid + v * 256;
            int kk = i >> 7, col = i & 127;
            Bs[kk][col] = W1[(kt + kk) * F1 + col];
        }
        __syncthreads();
#pragma unroll
        for (int kk = 0; kk < 20; ++kk) {
            float a[8], b[8];
            *(float4*)&a[0] = *(const float4*)&As[kk][ry * 8];
            *(float4*)&a[4] = *(const float4*)&As[kk][ry * 8 + 4];
            *(float4*)&b[0] = *(const float4*)&Bs[kk][cx * 8];
            *(float4*)&b[4] = *(const float4*)&Bs[kk][cx * 8 + 4];
#pragma unroll
            for (int i = 0; i < 8; ++i)
#pragma unroll
                for (int j = 0; j < 8; ++j) acc[i][j] = fmaf(a[i], b[j], acc[i][j]);
        }
    }
#pragma unroll
    for (int i = 0; i < 8; ++i) {
        int row = rowbase + ry * 8 + i;
        if (row < n) {
            float dv = dinv[row];
            float o[8];
#pragma unroll
            for (int j = 0; j < 8; ++j) o[j] = acc[i][j] * dv;
            float* yp = y1 + (size_t)row * F1 + cx * 8;
            *(float4*)yp = *(float4*)&o[0];
            *(float4*)(yp + 4) = *(float4*)&o[4];
        }
    }
}

// ---------------- GEMM2: 256x64 tile, K_TILE=16, 8x8 micro-tile ----------------
__global__ __launch_bounds__(256) void gemm2_k(const float* __restrict__ h, const float* __restrict__ W2,
                                               const float* __restrict__ dinv, float* __restrict__ y2, int n) {
    __shared__ float As[16][260];
    __shared__ float Bs[16][64];
    int tid = threadIdx.x;
    int cx = tid & 7;
    int ry = tid >> 3;
    int rowbase = blockIdx.x * 256;
    float acc[8][8];
#pragma unroll
    for (int i = 0; i < 8; ++i)
#pragma unroll
        for (int j = 0; j < 8; ++j) acc[i][j] = 0.f;

    int grow = min(rowbase + tid, n - 1);
    const float* hrow = h + (size_t)grow * F1;

    for (int kt = 0; kt < F1; kt += 16) {
        __syncthreads();
        float4 t0 = *(const float4*)(hrow + kt);
        float4 t1 = *(const float4*)(hrow + kt + 4);
        float4 t2 = *(const float4*)(hrow + kt + 8);
        float4 t3 = *(const float4*)(hrow + kt + 12);
        As[0][tid] = t0.x;  As[1][tid] = t0.y;  As[2][tid] = t0.z;  As[3][tid] = t0.w;
        As[4][tid] = t1.x;  As[5][tid] = t1.y;  As[6][tid] = t1.z;  As[7][tid] = t1.w;
        As[8][tid] = t2.x;  As[9][tid] = t2.y;  As[10][tid] = t2.z; As[11][tid] = t2.w;
        As[12][tid] = t3.x; As[13][tid] = t3.y; As[14][tid] = t3.z; As[15][tid] = t3.w;
#pragma unroll
        for (int v = 0; v < 4; ++v) {
            int i = tid + v * 256;
            int kk = i >> 6, col = i & 63;
            Bs[kk][col] = W2[(kt + kk) * F2 + col];
        }
        __syncthreads();
#pragma unroll
        for (int kk = 0; kk < 16; ++kk) {
            float a[8], b[8];
            *(float4*)&a[0] = *(const float4*)&As[kk][ry * 8];
            *(float4*)&a[4] = *(const float4*)&As[kk][ry * 8 + 4];
            *(float4*)&b[0] = *(const float4*)&Bs[kk][cx * 8];
            *(float4*)&b[4] = *(const float4*)&Bs[kk][cx * 8 + 4];
#pragma unroll
            for (int i = 0; i < 8; ++i)
#pragma unroll
                for (int j = 0; j < 8; ++j) acc[i][j] = fmaf(a[i], b[j], acc[i][j]);
        }
    }
#pragma unroll
    for (int i = 0; i < 8; ++i) {
        int row = rowbase + ry * 8 + i;
        if (row < n) {
            float dv = dinv[row];
            float o[8];
#pragma unroll
            for (int j = 0; j < 8; ++j) o[j] = acc[i][j] * dv;
            float* yp = y2 + (size_t)row * F2 + cx * 8;
            *(float4*)yp = *(float4*)&o[0];
            *(float4*)(yp + 4) = *(float4*)&o[4];
        }
    }
}

// ---------------- Pull aggregation (CSR; wave-per-node; 8 gathers in flight) ----------------

__global__ __launch_bounds__(256) void agg1_k(const float* __restrict__ y1, const int* __restrict__ offs,
                                              const int* __restrict__ slots, const float* __restrict__ dinv,
                                              const float* __restrict__ b1, float* __restrict__ hrelu, int n) {
    int gtid = blockIdx.x * 256 + threadIdx.x;
    int wid = gtid >> 6, lane = threadIdx.x & 63;
    int nw = (gridDim.x * 256) >> 6;
    int c = lane * 2;
    for (int i = wid; i < n; i += nw) {
        int row = __builtin_amdgcn_readfirstlane(i);
        int beg = offs[row], end = offs[row + 1];
        float2 acc = *(const float2*)(y1 + (size_t)row * F1 + c);  // self-loop term
        int j = beg;
        while (j < end) {
            int m = min(64, end - j);
            int sv = (lane < m) ? slots[j + lane] : 0;
            int t = 0;
            for (; t + 8 <= m; t += 8) {
                float2 v0 = *(const float2*)(y1 + (size_t)__shfl(sv, t) * F1 + c);
                float2 v1 = *(const float2*)(y1 + (size_t)__shfl(sv, t + 1) * F1 + c);
                float2 v2 = *(const float2*)(y1 + (size_t)__shfl(sv, t + 2) * F1 + c);
                float2 v3 = *(const float2*)(y1 + (size_t)__shfl(sv, t + 3) * F1 + c);
                float2 v4 = *(const float2*)(y1 + (size_t)__shfl(sv, t + 4) * F1 + c);
                float2 v5 = *(const float2*)(y1 + (size_t)__shfl(sv, t + 5) * F1 + c);
                float2 v6 = *(const float2*)(y1 + (size_t)__shfl(sv, t + 6) * F1 + c);
                float2 v7 = *(const float2*)(y1 + (size_t)__shfl(sv, t + 7) * F1 + c);
                acc.x += ((v0.x + v1.x) + (v2.x + v3.x)) + ((v4.x + v5.x) + (v6.x + v7.x));
                acc.y += ((v0.y + v1.y) + (v2.y + v3.y)) + ((v4.y + v5.y) + (v6.y + v7.y));
            }
            for (; t < m; ++t) {
                float2 v = *(const float2*)(y1 + (size_t)__shfl(sv, t) * F1 + c);
                acc.x += v.x;
                acc.y += v.y;
            }
            j += m;
        }
        float dv = dinv[row];
        float2 bb = *(const float2*)(b1 + c);
        float2 hv;
        hv.x = fmaxf(fmaf(acc.x, dv, bb.x), 0.f);
        hv.y = fmaxf(fmaf(acc.y, dv, bb.y), 0.f);
        *(float2*)(hrelu + (size_t)row * F1 + c) = hv;
    }
}

__global__ __launch_bounds__(256) void agg2_k(const float* __restrict__ y2, const int* __restrict__ offs,
                                              const int* __restrict__ slots, const float* __restrict__ dinv,
                                              const float* __restrict__ b2, float* __restrict__ out, int n) {
    int gtid = blockIdx.x * 256 + threadIdx.x;
    int wid = gtid >> 6, lane = threadIdx.x & 63;
    int nw = (gridDim.x * 256) >> 6;
    for (int i = wid; i < n; i += nw) {
        int row = __builtin_amdgcn_readfirstlane(i);
        int beg = offs[row], end = offs[row + 1];
        float acc = y2[(size_t)row * F2 + lane];  // self-loop term
        int j = beg;
        while (j < end) {
            int m = min(64, end - j);
            int sv = (lane < m) ? slots[j + lane] : 0;
            int t = 0;
            for (; t + 8 <= m; t += 8) {
                float v0 = y2[(size_t)__shfl(sv, t) * F2 + lane];
                float v1 = y2[(size_t)__shfl(sv, t + 1) * F2 + lane];
                float v2 = y2[(size_t)__shfl(sv, t + 2) * F2 + lane];
                float v3 = y2[(size_t)__shfl(sv, t + 3) * F2 + lane];
                float v4 = y2[(size_t)__shfl(sv, t + 4) * F2 + lane];
                float v5 = y2[(size_t)__shfl(sv, t + 5) * F2 + lane];
                float v6 = y2[(size_t)__shfl(sv, t + 6) * F2 + lane];
                float v7 = y2[(size_t)__shfl(sv, t + 7) * F2 + lane];
                acc += ((v0 + v1) + (v2 + v3)) + ((v4 + v5) + (v6 + v7));
            }
            for (; t < m; ++t) acc += y2[(size_t)__shfl(sv, t) * F2 + lane];
            j += m;
        }
        out[(size_t)row * F2 + lane] = fmaf(acc, dinv[row], b2[lane]);
    }
}

// ---------------- launch ----------------

extern "C" void kernel_launch(void* const* d_in, const int* in_sizes, int n_in,
                              void* d_out, int out_size, void* d_ws, size_t ws_size,
                              hipStream_t stream) {
    const float* x  = (const float*)d_in[0];
    const int*   ei = (const int*)d_in[1];
    const float* W1 = (const float*)d_in[2];
    const float* b1 = (const float*)d_in[3];
    const float* W2 = (const float*)d_in[4];
    const float* b2 = (const float*)d_in[5];
    float* out = (float*)d_out;

    int n = in_sizes[0] / NF0;
    int E = in_sizes[1] / 2;
    const int* srcv = ei;      // edge_index[0]
    const int* dstv = ei + E;  // edge_index[1]
    int nb = (n + 127) >> 7;   // 128-node buckets (782 for n=100000; must be <=1024)

    char* ws = (char*)d_ws;
    size_t off = 0;
    auto alloc = [&](size_t bytes) -> void* {
        void* p = ws + off;
        off = (off + bytes + 255) & ~(size_t)255;
        return p;
    };
    float* dinv  = (float*)alloc((size_t)n * 4);
    int* cnt     = (int*)alloc((size_t)n * 4);
    int* offs    = (int*)alloc((size_t)(n + 1) * 4);
    int* bcnt    = (int*)alloc((size_t)(nb + 1) * 4);
    int* boffs   = (int*)alloc((size_t)(nb + 1) * 4);
    int* bcur    = (int*)alloc((size_t)(nb + 1) * 4);
    int* slots   = (int*)alloc((size_t)E * 4);
    float* y1    = (float*)alloc((size_t)n * F1 * 4);
    float* hrelu = (float*)alloc((size_t)n * F1 * 4);
    float* y2    = y1;          // y1 dead after agg1; reuse
    int* ebuf    = (int*)hrelu; // hrelu not written until agg1; ebuf dead after local_fill

    hipMemsetAsync(cnt, 0, (size_t)n * 4, stream);
    hist_k<<<4096, 256, 0, stream>>>(dstv, cnt, E);
    bucket_sum_k<<<nb, 128, 0, stream>>>(cnt, bcnt, n);
    bucket_scan_k<<<1, 1024, 0, stream>>>(bcnt, boffs, bcur, nb, E, offs, n);
    bscatter_k<<<4096, 256, 0, stream>>>(srcv, dstv, bcur, ebuf, E);
    local_fill_k<<<nb, 256, 0, stream>>>(cnt, boffs, ebuf, offs, dinv, slots, n);

    gemm1_k<<<(n + 127) / 128, 256, 0, stream>>>(x, W1, dinv, y1, n);
    agg1_k<<<2048, 256, 0, stream>>>(y1, offs, slots, dinv, b1, hrelu, n);
    gemm2_k<<<(n + 255) / 256, 256, 0, stream>>>(hrelu, W2, dinv, y2, n);
    agg2_k<<<2048, 256, 0, stream>>>(y2, offs, slots, dinv, b2, out, n);
}

// Round 7
// 771.399 us; speedup vs baseline: 2.0073x; 2.0073x over previous
//
#include <hip/hip_runtime.h>

#define NF0 300
#define F1 128
#define F2 64
#define BB 256          // binning blocks (power of 2)
#define BKT_SH 7        // 128 nodes per bucket

// ---------------- CSR build: per-block LDS hist -> 3-level scan -> exact-offset scatter ----

// Pass A: per-block histogram over buckets. hist[blk*nb + b], coalesced.
__global__ __launch_bounds__(256) void passA_k(const int* __restrict__ dst, int* __restrict__ hist,
                                               int E, int nb, int epb) {
    __shared__ int h[1024];
    for (int i = threadIdx.x; i < nb; i += 256) h[i] = 0;
    __syncthreads();
    int beg = blockIdx.x * epb, end = min(E, beg + epb);
    for (int i = beg + threadIdx.x; i < end; i += 256) atomicAdd(&h[dst[i] >> BKT_SH], 1);
    __syncthreads();
    for (int i = threadIdx.x; i < nb; i += 256) hist[blockIdx.x * nb + i] = h[i];
}

// Scan stage 1: exclusive scan within 1024-chunks of the bucket-major ordering
// i = b*BB + blk  ->  hist[blk*nb + b]
__global__ __launch_bounds__(1024) void scanA_k(const int* __restrict__ hist, int* __restrict__ base,
                                                int* __restrict__ partials, int M, int nb) {
    __shared__ int s[1024];
    int i = blockIdx.x * 1024 + threadIdx.x;
    int v = 0;
    if (i < M) { int b = i / BB, blk = i & (BB - 1); v = hist[blk * nb + b]; }
    s[threadIdx.x] = v;
    __syncthreads();
    for (int d = 1; d < 1024; d <<= 1) {
        int t = (threadIdx.x >= (unsigned)d) ? s[threadIdx.x - d] : 0;
        __syncthreads();
        s[threadIdx.x] += t;
        __syncthreads();
    }
    if (i < M) base[i] = s[threadIdx.x] - v;  // exclusive within chunk
    if (threadIdx.x == 1023) partials[blockIdx.x] = s[1023];
}

// Scan stage 2: single-block exclusive scan of chunk totals (nchunks <= 1024)
__global__ __launch_bounds__(1024) void scanB_k(int* __restrict__ partials, int nchunks) {
    __shared__ int s[1024];
    int v = (threadIdx.x < nchunks) ? partials[threadIdx.x] : 0;
    s[threadIdx.x] = v;
    __syncthreads();
    for (int d = 1; d < 1024; d <<= 1) {
        int t = (threadIdx.x >= (unsigned)d) ? s[threadIdx.x - d] : 0;
        __syncthreads();
        s[threadIdx.x] += t;
        __syncthreads();
    }
    if (threadIdx.x < nchunks) partials[threadIdx.x] = s[threadIdx.x] - v;
}

// Scan stage 3: add chunk bases; extract per-bucket offsets (blk==0 entries)
__global__ void scanC_k(int* __restrict__ base, const int* __restrict__ partials, int* __restrict__ boffs,
                        int M, int nb, int E, int* __restrict__ offs, int n) {
    int i = blockIdx.x * blockDim.x + threadIdx.x;
    if (i < M) {
        int v = base[i] + partials[i >> 10];
        base[i] = v;
        if ((i & (BB - 1)) == 0) boffs[i / BB] = v;
    }
    if (i == 0) { boffs[nb] = E; offs[n] = E; }
}

// Pass B: exact-offset scatter. Each block writes contiguous private runs -> no global atomics.
__global__ __launch_bounds__(256) void passB_k(const int* __restrict__ src, const int* __restrict__ dst,
                                               const int* __restrict__ base, int* __restrict__ ebuf,
                                               int E, int nb, int epb) {
    __shared__ int lcur[1024];
    for (int i = threadIdx.x; i < nb; i += 256) lcur[i] = base[i * BB + blockIdx.x];
    __syncthreads();
    int beg = blockIdx.x * epb, end = min(E, beg + epb);
    for (int i = beg + threadIdx.x; i < end; i += 256) {
        int d = dst[i];
        int p = atomicAdd(&lcur[d >> BKT_SH], 1);           // LDS atomic only
        ebuf[p] = (src[i] << BKT_SH) | (d & 127);
    }
}

// Per bucket: count 128 node degrees from segment, LDS scan -> offs/dinv, then LDS-cursor scatter.
__global__ __launch_bounds__(256) void local_fill_k(const int* __restrict__ boffs, const int* __restrict__ ebuf,
                                                    int* __restrict__ offs, float* __restrict__ dinv,
                                                    int* __restrict__ slots, int n) {
    __shared__ int lcnt[128];
    __shared__ int lval[128];
    __shared__ int lcur[128];
    int tid = threadIdx.x;
    int node0 = blockIdx.x << BKT_SH;
    int nn = min(128, n - node0);
    if (tid < 128) lcnt[tid] = 0;
    __syncthreads();
    int beg = boffs[blockIdx.x], end = boffs[blockIdx.x + 1];
    for (int j = beg + tid; j < end; j += 256) atomicAdd(&lcnt[ebuf[j] & 127], 1);
    __syncthreads();
    if (tid < 128) lval[tid] = lcnt[tid];
    __syncthreads();
    for (int d = 1; d < 128; d <<= 1) {
        int t = 0;
        if (tid < 128 && tid >= d) t = lval[tid - d];
        __syncthreads();
        if (tid < 128) lval[tid] += t;
        __syncthreads();
    }
    if (tid < 128) {
        int c = lcnt[tid];
        int excl = lval[tid] - c;
        if (tid < nn) {
            offs[node0 + tid] = beg + excl;
            dinv[node0 + tid] = rsqrtf((float)c + 1.0f);  // +1 self-loop
        }
        lcur[tid] = beg + excl;
    }
    __syncthreads();
    for (int j = beg + tid; j < end; j += 256) {
        int e = ebuf[j];
        int p = atomicAdd(&lcur[e & 127], 1);
        slots[p] = e >> BKT_SH;
    }
}

// ---------------- GEMM1: canonical LDS-tiled, 128x128 tile, 8x8 micro-tile ----------------
__global__ __launch_bounds__(256) void gemm1_k(const float* __restrict__ x, const float* __restrict__ W1,
                                               const float* __restrict__ dinv, float* __restrict__ y1, int n) {
    __shared__ float As[20][132];
    __shared__ float Bs[20][128];
    int tid = threadIdx.x;
    int cx = tid & 15;
    int ry = tid >> 4;
    int rowbase = blockIdx.x * 128;
    float acc[8][8];
#pragma unroll
    for (int i = 0; i < 8; ++i)
#pragma unroll
        for (int j = 0; j < 8; ++j) acc[i][j] = 0.f;

    int srow = tid >> 1;
    int shalf = tid & 1;
    int grow = min(rowbase + srow, n - 1);
    const float* xrow = x + (size_t)grow * NF0 + shalf * 10;

    for (int kt = 0; kt < NF0; kt += 20) {
        __syncthreads();
#pragma unroll
        for (int j = 0; j < 10; ++j) As[shalf * 10 + j][srow] = xrow[kt + j];
#pragma unroll
        for (int v = 0; v < 10; ++v) {
            int i = tid + v * 256;
            int kk = i >> 7, col = i & 127;
            Bs[kk][col] = W1[(kt + kk) * F1 + col];
        }
        __syncthreads();
#pragma unroll
        for (int kk = 0; kk < 20; ++kk) {
            float a[8], b[8];
            *(float4*)&a[0] = *(const float4*)&As[kk][ry * 8];
            *(float4*)&a[4] = *(const float4*)&As[kk][ry * 8 + 4];
            *(float4*)&b[0] = *(const float4*)&Bs[kk][cx * 8];
            *(float4*)&b[4] = *(const float4*)&Bs[kk][cx * 8 + 4];
#pragma unroll
            for (int i = 0; i < 8; ++i)
#pragma unroll
                for (int j = 0; j < 8; ++j) acc[i][j] = fmaf(a[i], b[j], acc[i][j]);
        }
    }
#pragma unroll
    for (int i = 0; i < 8; ++i) {
        int row = rowbase + ry * 8 + i;
        if (row < n) {
            float dv = dinv[row];
            float o[8];
#pragma unroll
            for (int j = 0; j < 8; ++j) o[j] = acc[i][j] * dv;
            float* yp = y1 + (size_t)row * F1 + cx * 8;
            *(float4*)yp = *(float4*)&o[0];
            *(float4*)(yp + 4) = *(float4*)&o[4];
        }
    }
}

// ---------------- GEMM2: 256x64 tile, K_TILE=16, 8x8 micro-tile ----------------
__global__ __launch_bounds__(256) void gemm2_k(const float* __restrict__ h, const float* __restrict__ W2,
                                               const float* __restrict__ dinv, float* __restrict__ y2, int n) {
    __shared__ float As[16][260];
    __shared__ float Bs[16][64];
    int tid = threadIdx.x;
    int cx = tid & 7;
    int ry = tid >> 3;
    int rowbase = blockIdx.x * 256;
    float acc[8][8];
#pragma unroll
    for (int i = 0; i < 8; ++i)
#pragma unroll
        for (int j = 0; j < 8; ++j) acc[i][j] = 0.f;

    int grow = min(rowbase + tid, n - 1);
    const float* hrow = h + (size_t)grow * F1;

    for (int kt = 0; kt < F1; kt += 16) {
        __syncthreads();
        float4 t0 = *(const float4*)(hrow + kt);
        float4 t1 = *(const float4*)(hrow + kt + 4);
        float4 t2 = *(const float4*)(hrow + kt + 8);
        float4 t3 = *(const float4*)(hrow + kt + 12);
        As[0][tid] = t0.x;  As[1][tid] = t0.y;  As[2][tid] = t0.z;  As[3][tid] = t0.w;
        As[4][tid] = t1.x;  As[5][tid] = t1.y;  As[6][tid] = t1.z;  As[7][tid] = t1.w;
        As[8][tid] = t2.x;  As[9][tid] = t2.y;  As[10][tid] = t2.z; As[11][tid] = t2.w;
        As[12][tid] = t3.x; As[13][tid] = t3.y; As[14][tid] = t3.z; As[15][tid] = t3.w;
#pragma unroll
        for (int v = 0; v < 4; ++v) {
            int i = tid + v * 256;
            int kk = i >> 6, col = i & 63;
            Bs[kk][col] = W2[(kt + kk) * F2 + col];
        }
        __syncthreads();
#pragma unroll
        for (int kk = 0; kk < 16; ++kk) {
            float a[8], b[8];
            *(float4*)&a[0] = *(const float4*)&As[kk][ry * 8];
            *(float4*)&a[4] = *(const float4*)&As[kk][ry * 8 + 4];
            *(float4*)&b[0] = *(const float4*)&Bs[kk][cx * 8];
            *(float4*)&b[4] = *(const float4*)&Bs[kk][cx * 8 + 4];
#pragma unroll
            for (int i = 0; i < 8; ++i)
#pragma unroll
                for (int j = 0; j < 8; ++j) acc[i][j] = fmaf(a[i], b[j], acc[i][j]);
        }
    }
#pragma unroll
    for (int i = 0; i < 8; ++i) {
        int row = rowbase + ry * 8 + i;
        if (row < n) {
            float dv = dinv[row];
            float o[8];
#pragma unroll
            for (int j = 0; j < 8; ++j) o[j] = acc[i][j] * dv;
            float* yp = y2 + (size_t)row * F2 + cx * 8;
            *(float4*)yp = *(float4*)&o[0];
            *(float4*)(yp + 4) = *(float4*)&o[4];
        }
    }
}

// ---------------- Pull aggregation (CSR; wave-per-node; 8 gathers in flight) ----------------

__global__ __launch_bounds__(256) void agg1_k(const float* __restrict__ y1, const int* __restrict__ offs,
                                              const int* __restrict__ slots, const float* __restrict__ dinv,
                                              const float* __restrict__ b1, float* __restrict__ hrelu, int n) {
    int gtid = blockIdx.x * 256 + threadIdx.x;
    int wid = gtid >> 6, lane = threadIdx.x & 63;
    int nw = (gridDim.x * 256) >> 6;
    int c = lane * 2;
    for (int i = wid; i < n; i += nw) {
        int row = __builtin_amdgcn_readfirstlane(i);
        int beg = offs[row], end = offs[row + 1];
        float2 acc = *(const float2*)(y1 + (size_t)row * F1 + c);  // self-loop term
        int j = beg;
        while (j < end) {
            int m = min(64, end - j);
            int sv = (lane < m) ? slots[j + lane] : 0;
            int t = 0;
            for (; t + 8 <= m; t += 8) {
                float2 v0 = *(const float2*)(y1 + (size_t)__shfl(sv, t) * F1 + c);
                float2 v1 = *(const float2*)(y1 + (size_t)__shfl(sv, t + 1) * F1 + c);
                float2 v2 = *(const float2*)(y1 + (size_t)__shfl(sv, t + 2) * F1 + c);
                float2 v3 = *(const float2*)(y1 + (size_t)__shfl(sv, t + 3) * F1 + c);
                float2 v4 = *(const float2*)(y1 + (size_t)__shfl(sv, t + 4) * F1 + c);
                float2 v5 = *(const float2*)(y1 + (size_t)__shfl(sv, t + 5) * F1 + c);
                float2 v6 = *(const float2*)(y1 + (size_t)__shfl(sv, t + 6) * F1 + c);
                float2 v7 = *(const float2*)(y1 + (size_t)__shfl(sv, t + 7) * F1 + c);
                acc.x += ((v0.x + v1.x) + (v2.x + v3.x)) + ((v4.x + v5.x) + (v6.x + v7.x));
                acc.y += ((v0.y + v1.y) + (v2.y + v3.y)) + ((v4.y + v5.y) + (v6.y + v7.y));
            }
            for (; t < m; ++t) {
                float2 v = *(const float2*)(y1 + (size_t)__shfl(sv, t) * F1 + c);
                acc.x += v.x;
                acc.y += v.y;
            }
            j += m;
        }
        float dv = dinv[row];
        float2 bb = *(const float2*)(b1 + c);
        float2 hv;
        hv.x = fmaxf(fmaf(acc.x, dv, bb.x), 0.f);
        hv.y = fmaxf(fmaf(acc.y, dv, bb.y), 0.f);
        *(float2*)(hrelu + (size_t)row * F1 + c) = hv;
    }
}

__global__ __launch_bounds__(256) void agg2_k(const float* __restrict__ y2, const int* __restrict__ offs,
                                              const int* __restrict__ slots, const float* __restrict__ dinv,
                                              const float* __restrict__ b2, float* __restrict__ out, int n) {
    int gtid = blockIdx.x * 256 + threadIdx.x;
    int wid = gtid >> 6, lane = threadIdx.x & 63;
    int nw = (gridDim.x * 256) >> 6;
    for (int i = wid; i < n; i += nw) {
        int row = __builtin_amdgcn_readfirstlane(i);
        int beg = offs[row], end = offs[row + 1];
        float acc = y2[(size_t)row * F2 + lane];  // self-loop term
        int j = beg;
        while (j < end) {
            int m = min(64, end - j);
            int sv = (lane < m) ? slots[j + lane] : 0;
            int t = 0;
            for (; t + 8 <= m; t += 8) {
                float v0 = y2[(size_t)__shfl(sv, t) * F2 + lane];
                float v1 = y2[(size_t)__shfl(sv, t + 1) * F2 + lane];
                float v2 = y2[(size_t)__shfl(sv, t + 2) * F2 + lane];
                float v3 = y2[(size_t)__shfl(sv, t + 3) * F2 + lane];
                float v4 = y2[(size_t)__shfl(sv, t + 4) * F2 + lane];
                float v5 = y2[(size_t)__shfl(sv, t + 5) * F2 + lane];
                float v6 = y2[(size_t)__shfl(sv, t + 6) * F2 + lane];
                float v7 = y2[(size_t)__shfl(sv, t + 7) * F2 + lane];
                acc += ((v0 + v1) + (v2 + v3)) + ((v4 + v5) + (v6 + v7));
            }
            for (; t < m; ++t) acc += y2[(size_t)__shfl(sv, t) * F2 + lane];
            j += m;
        }
        out[(size_t)row * F2 + lane] = fmaf(acc, dinv[row], b2[lane]);
    }
}

// ---------------- launch ----------------

extern "C" void kernel_launch(void* const* d_in, const int* in_sizes, int n_in,
                              void* d_out, int out_size, void* d_ws, size_t ws_size,
                              hipStream_t stream) {
    const float* x  = (const float*)d_in[0];
    const int*   ei = (const int*)d_in[1];
    const float* W1 = (const float*)d_in[2];
    const float* b1 = (const float*)d_in[3];
    const float* W2 = (const float*)d_in[4];
    const float* b2 = (const float*)d_in[5];
    float* out = (float*)d_out;

    int n = in_sizes[0] / NF0;
    int E = in_sizes[1] / 2;
    const int* srcv = ei;      // edge_index[0]
    const int* dstv = ei + E;  // edge_index[1]
    int nb = (n + 127) >> BKT_SH;        // 782 buckets (<=1024)
    int M = nb * BB;                     // scan length
    int mchunks = (M + 1023) >> 10;      // <=1024
    int epb = (E + BB - 1) / BB;

    char* ws = (char*)d_ws;
    size_t off = 0;
    auto alloc = [&](size_t bytes) -> void* {
        void* p = ws + off;
        off = (off + bytes + 255) & ~(size_t)255;
        return p;
    };
    float* dinv   = (float*)alloc((size_t)n * 4);
    int* offs     = (int*)alloc((size_t)(n + 1) * 4);
    int* hist     = (int*)alloc((size_t)M * 4);
    int* base     = (int*)alloc((size_t)M * 4);
    int* partials = (int*)alloc((size_t)mchunks * 4);
    int* boffs    = (int*)alloc((size_t)(nb + 1) * 4);
    int* slots    = (int*)alloc((size_t)E * 4);
    float* y1     = (float*)alloc((size_t)n * F1 * 4);
    float* hrelu  = (float*)alloc((size_t)n * F1 * 4);
    float* y2     = y1;          // y1 dead after agg1; reuse
    int* ebuf     = (int*)hrelu; // hrelu unused until agg1; ebuf dead by then

    passA_k<<<BB, 256, 0, stream>>>(dstv, hist, E, nb, epb);
    scanA_k<<<mchunks, 1024, 0, stream>>>(hist, base, partials, M, nb);
    scanB_k<<<1, 1024, 0, stream>>>(partials, mchunks);
    scanC_k<<<(M + 255) / 256, 256, 0, stream>>>(base, partials, boffs, M, nb, E, offs, n);
    passB_k<<<BB, 256, 0, stream>>>(srcv, dstv, base, ebuf, E, nb, epb);
    local_fill_k<<<nb, 256, 0, stream>>>(boffs, ebuf, offs, dinv, slots, n);

    gemm1_k<<<(n + 127) / 128, 256, 0, stream>>>(x, W1, dinv, y1, n);
    agg1_k<<<2048, 256, 0, stream>>>(y1, offs, slots, dinv, b1, hrelu, n);
    gemm2_k<<<(n + 255) / 256, 256, 0, stream>>>(hrelu, W2, dinv, y2, n);
    agg2_k<<<2048, 256, 0, stream>>>(y2, offs, slots, dinv, b2, out, n);
}

// Round 11
// 623.066 us; speedup vs baseline: 2.4851x; 1.2381x over previous
//
#include <hip/hip_runtime.h>

#define NF0 300
#define F1 128
#define F2 64
#define BB 256          // binning blocks (power of 2)
#define BKT_SH 7        // 128 nodes per bucket

// bf16 helpers (RNE pack, cheap unpack)
__device__ inline unsigned bp(float f) {
    unsigned u = __float_as_uint(f);
    return (u + 0x7fffu + ((u >> 16) & 1u)) >> 16;
}
__device__ inline unsigned bp2(float lo, float hi) { return (bp(hi) << 16) | bp(lo); }
__device__ inline float bl(unsigned v) { return __uint_as_float(v << 16); }
__device__ inline float bh(unsigned v) { return __uint_as_float(v & 0xffff0000u); }

// ---------------- CSR build: per-block LDS hist -> 3-level scan -> exact-offset scatter ----

__global__ __launch_bounds__(256) void passA_k(const int* __restrict__ dst, int* __restrict__ hist,
                                               int E, int nb, int epb) {
    __shared__ int h[1024];
    for (int i = threadIdx.x; i < nb; i += 256) h[i] = 0;
    __syncthreads();
    int beg = blockIdx.x * epb, end = min(E, beg + epb);
    for (int i = beg + threadIdx.x; i < end; i += 256) atomicAdd(&h[dst[i] >> BKT_SH], 1);
    __syncthreads();
    for (int i = threadIdx.x; i < nb; i += 256) hist[blockIdx.x * nb + i] = h[i];
}

__global__ __launch_bounds__(1024) void scanA_k(const int* __restrict__ hist, int* __restrict__ base,
                                                int* __restrict__ partials, int M, int nb) {
    __shared__ int s[1024];
    int i = blockIdx.x * 1024 + threadIdx.x;
    int v = 0;
    if (i < M) { int b = i / BB, blk = i & (BB - 1); v = hist[blk * nb + b]; }
    s[threadIdx.x] = v;
    __syncthreads();
    for (int d = 1; d < 1024; d <<= 1) {
        int t = (threadIdx.x >= (unsigned)d) ? s[threadIdx.x - d] : 0;
        __syncthreads();
        s[threadIdx.x] += t;
        __syncthreads();
    }
    if (i < M) base[i] = s[threadIdx.x] - v;
    if (threadIdx.x == 1023) partials[blockIdx.x] = s[1023];
}

__global__ __launch_bounds__(1024) void scanB_k(int* __restrict__ partials, int nchunks) {
    __shared__ int s[1024];
    int v = (threadIdx.x < nchunks) ? partials[threadIdx.x] : 0;
    s[threadIdx.x] = v;
    __syncthreads();
    for (int d = 1; d < 1024; d <<= 1) {
        int t = (threadIdx.x >= (unsigned)d) ? s[threadIdx.x - d] : 0;
        __syncthreads();
        s[threadIdx.x] += t;
        __syncthreads();
    }
    if (threadIdx.x < nchunks) partials[threadIdx.x] = s[threadIdx.x] - v;
}

__global__ void scanC_k(int* __restrict__ base, const int* __restrict__ partials, int* __restrict__ boffs,
                        int M, int nb, int E, int* __restrict__ offs, int n) {
    int i = blockIdx.x * blockDim.x + threadIdx.x;
    if (i < M) {
        int v = base[i] + partials[i >> 10];
        base[i] = v;
        if ((i & (BB - 1)) == 0) boffs[i / BB] = v;
    }
    if (i == 0) { boffs[nb] = E; offs[n] = E; }
}

__global__ __launch_bounds__(256) void passB_k(const int* __restrict__ src, const int* __restrict__ dst,
                                               const int* __restrict__ base, int* __restrict__ ebuf,
                                               int E, int nb, int epb) {
    __shared__ int lcur[1024];
    for (int i = threadIdx.x; i < nb; i += 256) lcur[i] = base[i * BB + blockIdx.x];
    __syncthreads();
    int beg = blockIdx.x * epb, end = min(E, beg + epb);
    for (int i = beg + threadIdx.x; i < end; i += 256) {
        int d = dst[i];
        int p = atomicAdd(&lcur[d >> BKT_SH], 1);           // LDS atomic only
        ebuf[p] = (src[i] << BKT_SH) | (d & 127);
    }
}

__global__ __launch_bounds__(256) void local_fill_k(const int* __restrict__ boffs, const int* __restrict__ ebuf,
                                                    int* __restrict__ offs, float* __restrict__ dinv,
                                                    int* __restrict__ slots, int n) {
    __shared__ int lcnt[128];
    __shared__ int lval[128];
    __shared__ int lcur[128];
    int tid = threadIdx.x;
    int node0 = blockIdx.x << BKT_SH;
    int nn = min(128, n - node0);
    if (tid < 128) lcnt[tid] = 0;
    __syncthreads();
    int beg = boffs[blockIdx.x], end = boffs[blockIdx.x + 1];
    for (int j = beg + tid; j < end; j += 256) atomicAdd(&lcnt[ebuf[j] & 127], 1);
    __syncthreads();
    if (tid < 128) lval[tid] = lcnt[tid];
    __syncthreads();
    for (int d = 1; d < 128; d <<= 1) {
        int t = 0;
        if (tid < 128 && tid >= d) t = lval[tid - d];
        __syncthreads();
        if (tid < 128) lval[tid] += t;
        __syncthreads();
    }
    if (tid < 128) {
        int c = lcnt[tid];
        int excl = lval[tid] - c;
        if (tid < nn) {
            offs[node0 + tid] = beg + excl;
            dinv[node0 + tid] = rsqrtf((float)c + 1.0f);  // +1 self-loop
        }
        lcur[tid] = beg + excl;
    }
    __syncthreads();
    for (int j = beg + tid; j < end; j += 256) {
        int e = ebuf[j];
        int p = atomicAdd(&lcur[e & 127], 1);
        slots[p] = e >> BKT_SH;
    }
}

// ---------------- GEMM1: canonical LDS-tiled, 128x128 tile, 8x8 micro-tile; bf16-packed output ----
__global__ __launch_bounds__(256) void gemm1_k(const float* __restrict__ x, const float* __restrict__ W1,
                                               const float* __restrict__ dinv, unsigned* __restrict__ y1b, int n) {
    __shared__ float As[20][132];
    __shared__ float Bs[20][128];
    int tid = threadIdx.x;
    int cx = tid & 15;
    int ry = tid >> 4;
    int rowbase = blockIdx.x * 128;
    float acc[8][8];
#pragma unroll
    for (int i = 0; i < 8; ++i)
#pragma unroll
        for (int j = 0; j < 8; ++j) acc[i][j] = 0.f;

    int srow = tid >> 1;
    int shalf = tid & 1;
    int grow = min(rowbase + srow, n - 1);
    const float* xrow = x + (size_t)grow * NF0 + shalf * 10;

    for (int kt = 0; kt < NF0; kt += 20) {
        __syncthreads();
#pragma unroll
        for (int j = 0; j < 10; ++j) As[shalf * 10 + j][srow] = xrow[kt + j];
#pragma unroll
        for (int v = 0; v < 10; ++v) {
            int i = tid + v * 256;
            int kk = i >> 7, col = i & 127;
            Bs[kk][col] = W1[(kt + kk) * F1 + col];
        }
        __syncthreads();
#pragma unroll
        for (int kk = 0; kk < 20; ++kk) {
            float a[8], b[8];
            *(float4*)&a[0] = *(const float4*)&As[kk][ry * 8];
            *(float4*)&a[4] = *(const float4*)&As[kk][ry * 8 + 4];
            *(float4*)&b[0] = *(const float4*)&Bs[kk][cx * 8];
            *(float4*)&b[4] = *(const float4*)&Bs[kk][cx * 8 + 4];
#pragma unroll
            for (int i = 0; i < 8; ++i)
#pragma unroll
                for (int j = 0; j < 8; ++j) acc[i][j] = fmaf(a[i], b[j], acc[i][j]);
        }
    }
#pragma unroll
    for (int i = 0; i < 8; ++i) {
        int row = rowbase + ry * 8 + i;
        if (row < n) {
            float dv = dinv[row];
            uint4 o;
            o.x = bp2(acc[i][0] * dv, acc[i][1] * dv);
            o.y = bp2(acc[i][2] * dv, acc[i][3] * dv);
            o.z = bp2(acc[i][4] * dv, acc[i][5] * dv);
            o.w = bp2(acc[i][6] * dv, acc[i][7] * dv);
            *(uint4*)(y1b + (size_t)row * 64 + cx * 4) = o;  // cols 2c,2c+1 per uint
        }
    }
}

// ---------------- GEMM2: 256x64 tile, K_TILE=16, 8x8 micro-tile; bf16-packed output ----------------
__global__ __launch_bounds__(256) void gemm2_k(const float* __restrict__ h, const float* __restrict__ W2,
                                               const float* __restrict__ dinv, unsigned* __restrict__ y2b, int n) {
    __shared__ float As[16][260];
    __shared__ float Bs[16][64];
    int tid = threadIdx.x;
    int cx = tid & 7;
    int ry = tid >> 3;
    int rowbase = blockIdx.x * 256;
    float acc[8][8];
#pragma unroll
    for (int i = 0; i < 8; ++i)
#pragma unroll
        for (int j = 0; j < 8; ++j) acc[i][j] = 0.f;

    int grow = min(rowbase + tid, n - 1);
    const float* hrow = h + (size_t)grow * F1;

    for (int kt = 0; kt < F1; kt += 16) {
        __syncthreads();
        float4 t0 = *(const float4*)(hrow + kt);
        float4 t1 = *(const float4*)(hrow + kt + 4);
        float4 t2 = *(const float4*)(hrow + kt + 8);
        float4 t3 = *(const float4*)(hrow + kt + 12);
        As[0][tid] = t0.x;  As[1][tid] = t0.y;  As[2][tid] = t0.z;  As[3][tid] = t0.w;
        As[4][tid] = t1.x;  As[5][tid] = t1.y;  As[6][tid] = t1.z;  As[7][tid] = t1.w;
        As[8][tid] = t2.x;  As[9][tid] = t2.y;  As[10][tid] = t2.z; As[11][tid] = t2.w;
        As[12][tid] = t3.x; As[13][tid] = t3.y; As[14][tid] = t3.z; As[15][tid] = t3.w;
#pragma unroll
        for (int v = 0; v < 4; ++v) {
            int i = tid + v * 256;
            int kk = i >> 6, col = i & 63;
            Bs[kk][col] = W2[(kt + kk) * F2 + col];
        }
        __syncthreads();
#pragma unroll
        for (int kk = 0; kk < 16; ++kk) {
            float a[8], b[8];
            *(float4*)&a[0] = *(const float4*)&As[kk][ry * 8];
            *(float4*)&a[4] = *(const float4*)&As[kk][ry * 8 + 4];
            *(float4*)&b[0] = *(const float4*)&Bs[kk][cx * 8];
            *(float4*)&b[4] = *(const float4*)&Bs[kk][cx * 8 + 4];
#pragma unroll
            for (int i = 0; i < 8; ++i)
#pragma unroll
                for (int j = 0; j < 8; ++j) acc[i][j] = fmaf(a[i], b[j], acc[i][j]);
        }
    }
#pragma unroll
    for (int i = 0; i < 8; ++i) {
        int row = rowbase + ry * 8 + i;
        if (row < n) {
            float dv = dinv[row];
            uint4 o;
            o.x = bp2(acc[i][0] * dv, acc[i][1] * dv);
            o.y = bp2(acc[i][2] * dv, acc[i][3] * dv);
            o.z = bp2(acc[i][4] * dv, acc[i][5] * dv);
            o.w = bp2(acc[i][6] * dv, acc[i][7] * dv);
            *(uint4*)(y2b + (size_t)row * 32 + cx * 4) = o;  // ushort cols cx*8.. packed
        }
    }
}

// ---------------- Pull aggregation (CSR; wave-per-node; bf16 gathers, fp32 accumulate) --------

__global__ __launch_bounds__(256) void agg1_k(const unsigned* __restrict__ y1b, const int* __restrict__ offs,
                                              const int* __restrict__ slots, const float* __restrict__ dinv,
                                              const float* __restrict__ b1, float* __restrict__ hrelu, int n) {
    int gtid = blockIdx.x * 256 + threadIdx.x;
    int wid = gtid >> 6, lane = threadIdx.x & 63;
    int nw = (gridDim.x * 256) >> 6;
    for (int i = wid; i < n; i += nw) {
        int row = __builtin_amdgcn_readfirstlane(i);
        int beg = offs[row], end = offs[row + 1];
        unsigned vs = y1b[(size_t)row * 64 + lane];  // self-loop term
        float2 acc = {bl(vs), bh(vs)};
        int j = beg;
        while (j < end) {
            int m = min(64, end - j);
            int sv = (lane < m) ? slots[j + lane] : 0;
            int t = 0;
            for (; t + 8 <= m; t += 8) {  // 8 gathers in flight
                unsigned v0 = y1b[(size_t)__shfl(sv, t) * 64 + lane];
                unsigned v1 = y1b[(size_t)__shfl(sv, t + 1) * 64 + lane];
                unsigned v2 = y1b[(size_t)__shfl(sv, t + 2) * 64 + lane];
                unsigned v3 = y1b[(size_t)__shfl(sv, t + 3) * 64 + lane];
                unsigned v4 = y1b[(size_t)__shfl(sv, t + 4) * 64 + lane];
                unsigned v5 = y1b[(size_t)__shfl(sv, t + 5) * 64 + lane];
                unsigned v6 = y1b[(size_t)__shfl(sv, t + 6) * 64 + lane];
                unsigned v7 = y1b[(size_t)__shfl(sv, t + 7) * 64 + lane];
                acc.x += ((bl(v0) + bl(v1)) + (bl(v2) + bl(v3))) + ((bl(v4) + bl(v5)) + (bl(v6) + bl(v7)));
                acc.y += ((bh(v0) + bh(v1)) + (bh(v2) + bh(v3))) + ((bh(v4) + bh(v5)) + (bh(v6) + bh(v7)));
            }
            for (; t < m; ++t) {
                unsigned v = y1b[(size_t)__shfl(sv, t) * 64 + lane];
                acc.x += bl(v);
                acc.y += bh(v);
            }
            j += m;
        }
        float dv = dinv[row];
        int c = lane * 2;
        float2 bb = *(const float2*)(b1 + c);
        float2 hv;
        hv.x = fmaxf(fmaf(acc.x, dv, bb.x), 0.f);
        hv.y = fmaxf(fmaf(acc.y, dv, bb.y), 0.f);
        *(float2*)(hrelu + (size_t)row * F1 + c) = hv;
    }
}

__global__ __launch_bounds__(256) void agg2_k(const unsigned short* __restrict__ y2s, const int* __restrict__ offs,
                                              const int* __restrict__ slots, const float* __restrict__ dinv,
                                              const float* __restrict__ b2, float* __restrict__ out, int n) {
    int gtid = blockIdx.x * 256 + threadIdx.x;
    int wid = gtid >> 6, lane = threadIdx.x & 63;
    int nw = (gridDim.x * 256) >> 6;
    for (int i = wid; i < n; i += nw) {
        int row = __builtin_amdgcn_readfirstlane(i);
        int beg = offs[row], end = offs[row + 1];
        float acc = __uint_as_float(((unsigned)y2s[(size_t)row * 64 + lane]) << 16);  // self term
        int j = beg;
        while (j < end) {
            int m = min(64, end - j);
            int sv = (lane < m) ? slots[j + lane] : 0;
            int t = 0;
            for (; t + 8 <= m; t += 8) {
                unsigned v0 = y2s[(size_t)__shfl(sv, t) * 64 + lane];
                unsigned v1 = y2s[(size_t)__shfl(sv, t + 1) * 64 + lane];
                unsigned v2 = y2s[(size_t)__shfl(sv, t + 2) * 64 + lane];
                unsigned v3 = y2s[(size_t)__shfl(sv, t + 3) * 64 + lane];
                unsigned v4 = y2s[(size_t)__shfl(sv, t + 4) * 64 + lane];
                unsigned v5 = y2s[(size_t)__shfl(sv, t + 5) * 64 + lane];
                unsigned v6 = y2s[(size_t)__shfl(sv, t + 6) * 64 + lane];
                unsigned v7 = y2s[(size_t)__shfl(sv, t + 7) * 64 + lane];
                acc += ((__uint_as_float(v0 << 16) + __uint_as_float(v1 << 16)) +
                        (__uint_as_float(v2 << 16) + __uint_as_float(v3 << 16))) +
                       ((__uint_as_float(v4 << 16) + __uint_as_float(v5 << 16)) +
                        (__uint_as_float(v6 << 16) + __uint_as_float(v7 << 16)));
            }
            for (; t < m; ++t)
                acc += __uint_as_float(((unsigned)y2s[(size_t)__shfl(sv, t) * 64 + lane]) << 16);
            j += m;
        }
        out[(size_t)row * F2 + lane] = fmaf(acc, dinv[row], b2[lane]);
    }
}

// ---------------- launch ----------------

extern "C" void kernel_launch(void* const* d_in, const int* in_sizes, int n_in,
                              void* d_out, int out_size, void* d_ws, size_t ws_size,
                              hipStream_t stream) {
    const float* x  = (const float*)d_in[0];
    const int*   ei = (const int*)d_in[1];
    const float* W1 = (const float*)d_in[2];
    const float* b1 = (const float*)d_in[3];
    const float* W2 = (const float*)d_in[4];
    const float* b2 = (const float*)d_in[5];
    float* out = (float*)d_out;

    int n = in_sizes[0] / NF0;
    int E = in_sizes[1] / 2;
    const int* srcv = ei;      // edge_index[0]
    const int* dstv = ei + E;  // edge_index[1]
    int nb = (n + 127) >> BKT_SH;        // 782 buckets (<=1024)
    int M = nb * BB;
    int mchunks = (M + 1023) >> 10;
    int epb = (E + BB - 1) / BB;

    char* ws = (char*)d_ws;
    size_t off = 0;
    auto alloc = [&](size_t bytes) -> void* {
        void* p = ws + off;
        off = (off + bytes + 255) & ~(size_t)255;
        return p;
    };
    float* dinv    = (float*)alloc((size_t)n * 4);
    int* offs      = (int*)alloc((size_t)(n + 1) * 4);
    int* hist      = (int*)alloc((size_t)M * 4);
    int* base      = (int*)alloc((size_t)M * 4);
    int* partials  = (int*)alloc((size_t)mchunks * 4);
    int* boffs     = (int*)alloc((size_t)(nb + 1) * 4);
    int* slots     = (int*)alloc((size_t)E * 4);
    unsigned* y1b  = (unsigned*)alloc((size_t)n * 64 * 4);   // bf16x2 packed [n][64]
    float* hrelu   = (float*)alloc((size_t)n * F1 * 4);
    unsigned* y2b  = y1b;        // y1b dead after agg1; reuse for layer-2 packed output
    int* ebuf      = (int*)hrelu; // hrelu unused until agg1; ebuf dead by then

    passA_k<<<BB, 256, 0, stream>>>(dstv, hist, E, nb, epb);
    scanA_k<<<mchunks, 1024, 0, stream>>>(hist, base, partials, M, nb);
    scanB_k<<<1, 1024, 0, stream>>>(partials, mchunks);
    scanC_k<<<(M + 255) / 256, 256, 0, stream>>>(base, partials, boffs, M, nb, E, offs, n);
    passB_k<<<BB, 256, 0, stream>>>(srcv, dstv, base, ebuf, E, nb, epb);
    local_fill_k<<<nb, 256, 0, stream>>>(boffs, ebuf, offs, dinv, slots, n);

    gemm1_k<<<(n + 127) / 128, 256, 0, stream>>>(x, W1, dinv, y1b, n);
    agg1_k<<<2048, 256, 0, stream>>>(y1b, offs, slots, dinv, b1, hrelu, n);
    gemm2_k<<<(n + 255) / 256, 256, 0, stream>>>(hrelu, W2, dinv, y2b, n);
    agg2_k<<<2048, 256, 0, stream>>>((const unsigned short*)y2b, offs, slots, dinv, b2, out, n);
}